// Round 3
// baseline (1385.197 us; speedup 1.0000x reference)
//
#include <hip/hip_runtime.h>
#include <hip/hip_bf16.h>
#include <math.h>

#define NN 20000
#define NE 320000
#define NG 200
#define FI 75
#define NT 5
#define FO 15
#define CH 375     // NT*FI
#define PI 975

__device__ __forceinline__ void fma16(float u, const float* w, float* acc) {
  const float4* w4 = (const float4*)w;
  float4 a0 = w4[0], a1 = w4[1], a2 = w4[2], a3 = w4[3];
  acc[0] = fmaf(u, a0.x, acc[0]);  acc[1] = fmaf(u, a0.y, acc[1]);
  acc[2] = fmaf(u, a0.z, acc[2]);  acc[3] = fmaf(u, a0.w, acc[3]);
  acc[4] = fmaf(u, a1.x, acc[4]);  acc[5] = fmaf(u, a1.y, acc[5]);
  acc[6] = fmaf(u, a1.z, acc[6]);  acc[7] = fmaf(u, a1.w, acc[7]);
  acc[8] = fmaf(u, a2.x, acc[8]);  acc[9] = fmaf(u, a2.y, acc[9]);
  acc[10] = fmaf(u, a2.z, acc[10]); acc[11] = fmaf(u, a2.w, acc[11]);
  acc[12] = fmaf(u, a3.x, acc[12]); acc[13] = fmaf(u, a3.y, acc[13]);
  acc[14] = fmaf(u, a3.z, acc[14]); acc[15] = fmaf(u, a3.w, acc[15]);
}

// ---------------- prep ----------------
__global__ void k_gather_x(const int* __restrict__ xidx, const float* __restrict__ emb,
                           float* __restrict__ x) {
  int i = blockIdx.x * 256 + threadIdx.x;
  if (i < NN * FI) {
    int n = i / FI, f = i - n * FI;
    x[i] = emb[xidx[n] * FI + f];
  }
}

__global__ void k_count(const int* __restrict__ dst, int* __restrict__ deg) {
  int e = blockIdx.x * 256 + threadIdx.x;
  if (e < NE) atomicAdd(&deg[dst[e]], 1);
}

__global__ void k_scan(const int* __restrict__ deg, int* __restrict__ off,
                       int* __restrict__ cur) {
  __shared__ int buf[1024];
  __shared__ int carry;
  int tx = threadIdx.x;
  if (tx == 0) carry = 0;
  __syncthreads();
  for (int base = 0; base < NN; base += 1024) {
    int i = base + tx;
    int v = (i < NN) ? deg[i] : 0;
    buf[tx] = v;
    __syncthreads();
    for (int o = 1; o < 1024; o <<= 1) {
      int t = (tx >= o) ? buf[tx - o] : 0;
      __syncthreads();
      buf[tx] += t;
      __syncthreads();
    }
    if (i < NN) { int ex = carry + buf[tx] - v; off[i] = ex; cur[i] = ex; }
    __syncthreads();
    if (tx == 0) carry += buf[1023];
    __syncthreads();
  }
  if (tx == 0) off[NN] = carry;
}

__global__ void k_fill(const int* __restrict__ srcp, const int* __restrict__ dstp,
                       const int* __restrict__ attr, int* __restrict__ cur,
                       int2* __restrict__ csr) {
  int e = blockIdx.x * 256 + threadIdx.x;
  if (e < NE) {
    int pos = atomicAdd(&cur[dstp[e]], 1);
    csr[pos] = make_int2(srcp[e], attr[e]);
  }
}

__global__ void k_logsum(const int* __restrict__ deg, float* __restrict__ avglog) {
  __shared__ float red[1024];
  float s = 0.f;
  for (int i = threadIdx.x; i < NN; i += 1024) s += logf((float)deg[i] + 1.f);
  red[threadIdx.x] = s;
  __syncthreads();
  for (int o = 512; o > 0; o >>= 1) {
    if (threadIdx.x < o) red[threadIdx.x] += red[threadIdx.x + o];
    __syncthreads();
  }
  if (threadIdx.x == 0) avglog[0] = red[0] / (float)NN;
}

__global__ void k_scalers(const int* __restrict__ deg, const float* __restrict__ avglog,
                          float* __restrict__ amp, float* __restrict__ att,
                          float* __restrict__ inv) {
  int i = blockIdx.x * 256 + threadIdx.x;
  if (i < NN) {
    float dc = fmaxf((float)deg[i], 1.f);
    float ld = logf(dc + 1.f);
    float av = avglog[0];
    amp[i] = ld / av;
    att[i] = av / ld;
    inv[i] = 1.f / dc;
  }
}

// te[l,a,:] = edge_emb[a]@W_edge[l]+b_edge[l]
__global__ void k_table_e(const float* __restrict__ eemb, const float* __restrict__ W_edge,
                          const float* __restrict__ b_edge, float* __restrict__ te) {
  int la = blockIdx.x;               // l*100+a
  int l = la / 100, a = la - l * 100;
  int f = threadIdx.x;
  if (f < FI) {
    float acc = b_edge[l * FI + f];
    for (int j = 0; j < 50; ++j)
      acc = fmaf(eemb[a * 50 + j], W_edge[(l * 50 + j) * FI + f], acc);
    te[la * FI + f] = acc;
  }
}

// tm[l,a,c] = te[l,a]@W_pre[l,t,150:225,f] + b_pre[l,t,f],  c=t*75+f
__global__ void k_tbl_m(const float* __restrict__ te, const float* __restrict__ W_pre,
                        const float* __restrict__ b_pre, float* __restrict__ tm) {
  int la = blockIdx.x;
  int l = la / 100;
  int c = threadIdx.x;
  if (c < CH) {
    int t = c / FI, f = c - t * FI;
    float acc = b_pre[(l * NT + t) * FI + f];
    const float* ter = te + la * FI;
    for (int k = 0; k < FI; ++k)
      acc = fmaf(ter[k], W_pre[((size_t)(l * NT + t) * 225 + 150 + k) * FI + f], acc);
    tm[la * CH + c] = acc;
  }
}

// WAs[l,k,c] = W_pre src rows: W_pre[l, t, 75+k, f], c = t*75+f
__global__ void k_repack_WAs(const float* __restrict__ W_pre, float* __restrict__ WAs) {
  int i = blockIdx.x * 256 + threadIdx.x;
  if (i < 2 * FI * CH) {
    int c = i % CH;
    int k = (i / CH) % FI;
    int l = i / (CH * FI);
    int t = c / FI, f = c - t * FI;
    WAs[i] = W_pre[((size_t)(l * NT + t) * 225 + FI + k) * FI + f];
  }
}

// Wp[l,t,c,0:16] = W_post padded to 16 floats per row
__global__ void k_repack_Wpad(const float* __restrict__ W_post, float* __restrict__ Wp) {
  int i = blockIdx.x * 256 + threadIdx.x;
  if (i < 2 * NT * PI * 16) {
    int f = i & 15;
    int c = (i >> 4) % PI;
    int t = (i / (16 * PI)) % NT;
    int l = i / (16 * PI * NT);
    Wp[i] = (f < FO) ? W_post[((size_t)(l * NT + t) * PI + c) * FO + f] : 0.f;
  }
}

// V[l,t,g,j,f16] = sum_q W_pre_dst[l,t,j,q] * (W_post rows mean+min+max of scaler g)
__global__ void k_make_V(const float* __restrict__ W_pre, const float* __restrict__ W_post,
                         float* __restrict__ V) {
  int bid = blockIdx.x;              // (l*5+t)*3 + g
  int g = bid % 3;
  int lt = bid / 3;
  __shared__ float S[FI * 16];
  int tid = threadIdx.x;
  for (int idx = tid; idx < FI * 16; idx += 128) {
    int q = idx >> 4, f = idx & 15;
    float v = 0.f;
    if (f < FO) {
      const float* wb = W_post + (size_t)lt * PI * FO;
      int rowb = FI + g * 300 + q;
      v = wb[rowb * FO + f] + wb[(rowb + FI) * FO + f] + wb[(rowb + 2 * FI) * FO + f];
    }
    S[idx] = v;
  }
  __syncthreads();
  for (int idx = tid; idx < FI * 16; idx += 128) {
    int j = idx >> 4, f = idx & 15;
    float acc = 0.f;
    const float* wr = W_pre + ((size_t)lt * 225 + j) * FI;   // dst row j (rows 0:75)
    for (int q = 0; q < FI; ++q) acc = fmaf(wr[q], S[q * 16 + f], acc);
    V[((size_t)bid * FI + j) * 16 + f] = acc;
  }
}

// bc[l,g] = b_post_flat[l]@W_lin[l] + b_lin[l]
__global__ void k_bias_comb(const float* __restrict__ b_post, const float* __restrict__ W_lin,
                            const float* __restrict__ b_lin, float* __restrict__ bc) {
  int l = blockIdx.x;
  int g = threadIdx.x;
  if (g < FI) {
    float acc = b_lin[l * FI + g];
    for (int j = 0; j < FI; ++j)
      acc = fmaf(b_post[l * FI + j], W_lin[(l * FI + j) * FI + g], acc);
    bc[l * FI + g] = acc;
  }
}

// ---------------- per-layer ----------------
// xs[n, c] = x[n] @ W_pre_src  (c = t*75+f), tile 64 nodes x 128 ch
__global__ __launch_bounds__(256) void k_gemm_xs(const float* __restrict__ x,
                                                 const float* __restrict__ WsL,
                                                 float* __restrict__ xs) {
  __shared__ float Xs[64 * FI];
  __shared__ float Ws[FI * 128];
  int n0 = blockIdx.x * 64;
  int c0 = blockIdx.y * 128;
  int tid = threadIdx.x;
  for (int i = tid; i < 64 * FI; i += 256) {
    int n = n0 + i / FI;
    Xs[i] = (n < NN) ? x[(size_t)n0 * FI + i] : 0.f;
  }
  for (int i = tid; i < FI * 128; i += 256) {
    int k = i >> 7, cc = i & 127;
    Ws[i] = (c0 + cc < CH) ? WsL[k * CH + c0 + cc] : 0.f;
  }
  __syncthreads();
  int tx = tid & 31, ty = tid >> 5;  // ty 0..7
  float acc[8][4];
#pragma unroll
  for (int i = 0; i < 8; ++i)
#pragma unroll
    for (int j = 0; j < 4; ++j) acc[i][j] = 0.f;
  for (int k = 0; k < FI; ++k) {
    float a_[8], b_[4];
#pragma unroll
    for (int i = 0; i < 8; ++i) a_[i] = Xs[(ty + 8 * i) * FI + k];
#pragma unroll
    for (int j = 0; j < 4; ++j) b_[j] = Ws[k * 128 + tx + 32 * j];
#pragma unroll
    for (int i = 0; i < 8; ++i)
#pragma unroll
      for (int j = 0; j < 4; ++j) acc[i][j] = fmaf(a_[i], b_[j], acc[i][j]);
  }
#pragma unroll
  for (int i = 0; i < 8; ++i) {
    int n = n0 + ty + 8 * i;
    if (n < NN) {
#pragma unroll
      for (int j = 0; j < 4; ++j) {
        int c = c0 + tx + 32 * j;
        if (c < CH) xs[(size_t)n * CH + c] = acc[i][j];
      }
    }
  }
}

// per-node multi-aggregator reduction of z = xs[src] + tm[attr] (dst-shift folded into V)
__global__ __launch_bounds__(128) void k_aggregate(int n0,
    const float* __restrict__ xs, const int2* __restrict__ csr,
    const int* __restrict__ off, const float* __restrict__ inv_deg,
    const float* __restrict__ tblL, float* __restrict__ aggz) {
  int n = n0 + blockIdx.x;
  int tx = threadIdx.x;
  int o0 = off[n], o1 = off[n + 1];
  bool l2 = tx < (CH - 256);
  float s0 = 0, s1 = 0, s2 = 0, q0 = 0, q1 = 0, q2 = 0;
  float mn0 = INFINITY, mn1 = INFINITY, mn2 = INFINITY;
  float mx0 = -INFINITY, mx1 = -INFINITY, mx2 = -INFINITY;
  for (int i = o0; i < o1; ++i) {
    int2 e = csr[i];
    const float* xsp = xs + (size_t)e.x * CH;
    const float* tp = tblL + (size_t)e.y * CH;
    float z0 = xsp[tx] + tp[tx];
    s0 += z0; q0 = fmaf(z0, z0, q0); mn0 = fminf(mn0, z0); mx0 = fmaxf(mx0, z0);
    float z1 = xsp[tx + 128] + tp[tx + 128];
    s1 += z1; q1 = fmaf(z1, z1, q1); mn1 = fminf(mn1, z1); mx1 = fmaxf(mx1, z1);
    if (l2) {
      float z2 = xsp[tx + 256] + tp[tx + 256];
      s2 += z2; q2 = fmaf(z2, z2, q2); mn2 = fminf(mn2, z2); mx2 = fmaxf(mx2, z2);
    }
  }
  if (o1 == o0) { mn0 = mn1 = mn2 = 0.f; mx0 = mx1 = mx2 = 0.f; }
  float inv = inv_deg[n];
  float me0 = s0 * inv, me1 = s1 * inv, me2 = s2 * inv;
  float sd0 = sqrtf(fmaxf(q0 * inv - me0 * me0, 0.f) + 1e-5f);
  float sd1 = sqrtf(fmaxf(q1 * inv - me1 * me1, 0.f) + 1e-5f);
  float sd2 = sqrtf(fmaxf(q2 * inv - me2 * me2, 0.f) + 1e-5f);
  float* base = aggz + (size_t)(n - n0) * 1500;
  base[0 * CH + tx] = me0; base[1 * CH + tx] = mn0;
  base[2 * CH + tx] = mx0; base[3 * CH + tx] = sd0;
  base[0 * CH + tx + 128] = me1; base[1 * CH + tx + 128] = mn1;
  base[2 * CH + tx + 128] = mx1; base[3 * CH + tx + 128] = sd1;
  if (l2) {
    base[0 * CH + tx + 256] = me2; base[1 * CH + tx + 256] = mn2;
    base[2 * CH + tx + 256] = mx2; base[3 * CH + tx + 256] = sd2;
  }
}

// post towers (975->15 each) + dst-shift via V + shared lin (75->75) + BN partials
__global__ __launch_bounds__(192) void k_post(int n0, int n1,
    const float* __restrict__ x, const float* __restrict__ aggz,
    const float* __restrict__ amp, const float* __restrict__ att,
    const int* __restrict__ deg,
    const float* __restrict__ WpL, const float* __restrict__ VL,
    const float* __restrict__ W_linL, const float* __restrict__ bcL,
    float* __restrict__ yout, float* __restrict__ bnsum) {
  __shared__ float ytile[32][77];
  __shared__ float ysum[FI], ysq[FI];
  int tid = threadIdx.x;
  if (tid < FI) { ysum[tid] = 0.f; ysq[tid] = 0.f; }
  int nl = tid & 31, t = tid >> 5;   // t 0..5 (t==5 idle)
  int n = n0 + blockIdx.x * 32 + nl;
  bool act = (t < NT) && (n < n1);
  float acc[16];
#pragma unroll
  for (int f = 0; f < 16; ++f) acc[f] = 0.f;
  if (act) {
    const float* wp = WpL + (size_t)t * PI * 16;
    const float* Vt = VL + (size_t)t * 3 * FI * 16;
    const float* xp = x + (size_t)n * FI;
    float hi = (deg[n] > 0) ? 1.f : 0.f;
    float ampn = amp[n], attn = att[n];
    float an = ampn * hi, at_ = attn * hi;
    for (int k = 0; k < FI; ++k) {
      float u = xp[k];
      fma16(u, wp + k * 16, acc);            // self x block (always)
      fma16(u * hi, Vt + k * 16, acc);       // xd * (mean+min+max), identity scaler
      fma16(u * an, Vt + (FI + k) * 16, acc);      // * amp
      fma16(u * at_, Vt + (2 * FI + k) * 16, acc); // * att
    }
    float sc[3];
    sc[0] = 1.f; sc[1] = ampn; sc[2] = attn;
    const float* ap = aggz + (size_t)(n - n0) * 1500;
    for (int g = 0; g < 3; ++g) {
      float s = sc[g];
      for (int a = 0; a < 4; ++a) {
        const float* ar = ap + a * CH + t * FI;
        const float* wseg = wp + (size_t)(FI + g * 300 + a * FI) * 16;
        for (int k = 0; k < FI; ++k) fma16(s * ar[k], wseg + k * 16, acc);
      }
    }
#pragma unroll
    for (int f = 0; f < FO; ++f) ytile[nl][t * FO + f] = acc[f];
  }
  __syncthreads();
  if (act) {
    float out[FO];
#pragma unroll
    for (int f = 0; f < FO; ++f) out[f] = 0.f;
    for (int j = 0; j < FI; ++j) {
      float yv = ytile[nl][j];
      const float* wr = W_linL + j * FI + t * FO;
#pragma unroll
      for (int f = 0; f < FO; ++f) out[f] = fmaf(yv, wr[f], out[f]);
    }
#pragma unroll
    for (int f = 0; f < FO; ++f) {
      int g = t * FO + f;
      float v = out[f] + bcL[g];
      yout[(size_t)n * FI + g] = v;
      atomicAdd(&ysum[g], v);
      atomicAdd(&ysq[g], v * v);
    }
  }
  __syncthreads();
  if (tid < FI) {
    atomicAdd(&bnsum[tid], ysum[tid]);
    atomicAdd(&bnsum[FI + tid], ysq[tid]);
  }
}

__global__ void k_bnfin(const float* __restrict__ bnsum, const float* __restrict__ gamL,
                        const float* __restrict__ betL, float* __restrict__ bnsc) {
  int f = threadIdx.x;
  if (f < FI) {
    float mu = bnsum[f] / (float)NN;
    float var = bnsum[FI + f] / (float)NN - mu * mu;
    float scl = gamL[f] * rsqrtf(var + 1e-5f);
    bnsc[f] = scl;
    bnsc[FI + f] = betL[f] - mu * scl;
  }
}

__global__ void k_bnapply(const float* __restrict__ y, const float* __restrict__ bnsc,
                          float* __restrict__ xo) {
  int i = blockIdx.x * 256 + threadIdx.x;
  if (i < NN * FI) {
    int f = i % FI;
    xo[i] = fmaxf(fmaf(y[i], bnsc[f], bnsc[FI + f]), 0.f);
  }
}

// ---------------- readout ----------------
__global__ void k_pool(const float* __restrict__ x, const int* __restrict__ batch,
                       float* __restrict__ pooled) {
  int i = blockIdx.x * 256 + threadIdx.x;
  if (i < NN * FI) {
    int n = i / FI, f = i - n * FI;
    atomicAdd(&pooled[batch[n] * FI + f], x[i]);
  }
}

__global__ void k_head(const float* __restrict__ pooled, const float* __restrict__ W1,
                       const float* __restrict__ b1, const float* __restrict__ W2,
                       const float* __restrict__ b2, const float* __restrict__ W3,
                       const float* __restrict__ b3, float* __restrict__ out) {
  __shared__ float p[FI], h1[50], h2[25];
  int g = blockIdx.x, t = threadIdx.x;
  for (int i = t; i < FI; i += 64) p[i] = pooled[g * FI + i];
  __syncthreads();
  if (t < 50) {
    float a = b1[t];
    for (int j = 0; j < FI; ++j) a = fmaf(p[j], W1[j * 50 + t], a);
    h1[t] = fmaxf(a, 0.f);
  }
  __syncthreads();
  if (t < 25) {
    float a = b2[t];
    for (int j = 0; j < 50; ++j) a = fmaf(h1[j], W2[j * 25 + t], a);
    h2[t] = fmaxf(a, 0.f);
  }
  __syncthreads();
  if (t == 0) {
    float a = b3[0];
    for (int j = 0; j < 25; ++j) a = fmaf(h2[j], W3[j], a);
    out[g] = a;
  }
}

extern "C" void kernel_launch(void* const* d_in, const int* in_sizes, int n_in,
                              void* d_out, int out_size, void* d_ws, size_t ws_size,
                              hipStream_t stream) {
  const int* x_idx = (const int*)d_in[0];
  const int* eidx  = (const int*)d_in[1];
  const int* srcp  = eidx;
  const int* dstp  = eidx + NE;
  const int* eattr = (const int*)d_in[2];
  const int* batch = (const int*)d_in[3];
  const float* node_emb = (const float*)d_in[4];
  const float* edge_emb = (const float*)d_in[5];
  const float* W_edge = (const float*)d_in[6];
  const float* b_edge = (const float*)d_in[7];
  const float* W_pre  = (const float*)d_in[8];
  const float* b_pre  = (const float*)d_in[9];
  const float* W_post = (const float*)d_in[10];
  const float* b_post = (const float*)d_in[11];
  const float* W_lin  = (const float*)d_in[12];
  const float* b_lin  = (const float*)d_in[13];
  const float* gam = (const float*)d_in[14];
  const float* bet = (const float*)d_in[15];
  const float* W1 = (const float*)d_in[16];
  const float* b1 = (const float*)d_in[17];
  const float* W2 = (const float*)d_in[18];
  const float* b2 = (const float*)d_in[19];
  const float* W3 = (const float*)d_in[20];
  const float* b3 = (const float*)d_in[21];

  char* p = (char*)d_ws;
  auto alloc = [&](size_t b) -> char* {
    char* r = p;
    p += (b + 255) & ~(size_t)255;
    return r;
  };
  float* x_a   = (float*)alloc((size_t)NN * FI * 4);
  float* x_b   = (float*)alloc((size_t)NN * FI * 4);
  float* xs    = (float*)alloc((size_t)NN * CH * 4);      // src projection only
  float* te    = (float*)alloc(2 * 100 * FI * 4);
  float* tm    = (float*)alloc(2 * 100 * CH * 4);
  float* WAs   = (float*)alloc((size_t)2 * FI * CH * 4);
  float* Wp    = (float*)alloc((size_t)2 * NT * PI * 16 * 4);
  float* V     = (float*)alloc((size_t)2 * NT * 3 * FI * 16 * 4);
  float* bc    = (float*)alloc(2 * FI * 4);
  float* ampv  = (float*)alloc((size_t)NN * 4);
  float* attv  = (float*)alloc((size_t)NN * 4);
  float* invv  = (float*)alloc((size_t)NN * 4);
  float* avglog = (float*)alloc(256);
  float* bnsum = (float*)alloc(2 * FI * 4);
  float* bnsc  = (float*)alloc(2 * FI * 4);
  float* pooled = (float*)alloc((size_t)NG * FI * 4);
  int* deg = (int*)alloc((size_t)NN * 4);
  int* off = (int*)alloc((size_t)(NN + 1) * 4);
  int* cur = (int*)alloc((size_t)NN * 4);
  int2* csr = (int2*)alloc((size_t)NE * 8);
  size_t used = (size_t)(p - (char*)d_ws);
  // z-stat buffer: chunk nodes so everything fits in ws_size (deterministic per ws_size)
  int chunkN = NN;
  while (chunkN > 625 && used + (size_t)chunkN * 1500 * 4 + (1 << 20) > ws_size)
    chunkN >>= 1;   // 20000 -> 10000 -> 5000 -> 2500 -> 1250 -> 625
  float* aggz = (float*)alloc((size_t)chunkN * 1500 * 4);

  hipMemsetAsync(deg, 0, (size_t)NN * 4, stream);
  hipMemsetAsync(pooled, 0, (size_t)NG * FI * 4, stream);

  k_gather_x<<<(NN * FI + 255) / 256, 256, 0, stream>>>(x_idx, node_emb, x_a);
  k_count<<<(NE + 255) / 256, 256, 0, stream>>>(dstp, deg);
  k_scan<<<1, 1024, 0, stream>>>(deg, off, cur);
  k_fill<<<(NE + 255) / 256, 256, 0, stream>>>(srcp, dstp, eattr, cur, csr);
  k_logsum<<<1, 1024, 0, stream>>>(deg, avglog);
  k_scalers<<<(NN + 255) / 256, 256, 0, stream>>>(deg, avglog, ampv, attv, invv);
  k_table_e<<<200, 128, 0, stream>>>(edge_emb, W_edge, b_edge, te);
  k_tbl_m<<<200, 384, 0, stream>>>(te, W_pre, b_pre, tm);
  k_repack_WAs<<<(2 * FI * CH + 255) / 256, 256, 0, stream>>>(W_pre, WAs);
  k_repack_Wpad<<<(2 * NT * PI * 16 + 255) / 256, 256, 0, stream>>>(W_post, Wp);
  k_make_V<<<2 * NT * 3, 128, 0, stream>>>(W_pre, W_post, V);
  k_bias_comb<<<2, 128, 0, stream>>>(b_post, W_lin, b_lin, bc);

  for (int l = 0; l < 2; ++l) {
    const float* xin = (l == 0) ? x_a : x_b;
    float* xout = (l == 0) ? x_b : x_a;
    k_gemm_xs<<<dim3(313, 3), 256, 0, stream>>>(xin, WAs + (size_t)l * FI * CH, xs);
    hipMemsetAsync(bnsum, 0, 2 * FI * 4, stream);
    for (int n0 = 0; n0 < NN; n0 += chunkN) {
      int cn = (NN - n0 < chunkN) ? (NN - n0) : chunkN;
      k_aggregate<<<cn, 128, 0, stream>>>(n0, xs, csr, off, invv,
                                          tm + (size_t)l * 100 * CH, aggz);
      k_post<<<(cn + 31) / 32, 192, 0, stream>>>(
          n0, n0 + cn, xin, aggz, ampv, attv, deg,
          Wp + (size_t)l * NT * PI * 16, V + (size_t)l * NT * 3 * FI * 16,
          W_lin + l * FI * FI, bc + l * FI, xout, bnsum);
    }
    k_bnfin<<<1, 128, 0, stream>>>(bnsum, gam + l * FI, bet + l * FI, bnsc);
    k_bnapply<<<(NN * FI + 255) / 256, 256, 0, stream>>>(xout, bnsc, xout);
  }

  k_pool<<<(NN * FI + 255) / 256, 256, 0, stream>>>(x_a, batch, pooled);
  k_head<<<NG, 64, 0, stream>>>(pooled, W1, b1, W2, b2, W3, b3, (float*)d_out);
}

// Round 4
// 651.978 us; speedup vs baseline: 2.1246x; 2.1246x over previous
//
#include <hip/hip_runtime.h>
#include <hip/hip_bf16.h>
#include <math.h>

#define NN 20000
#define NE 320000
#define NG 200
#define FI 75
#define NT 5
#define FO 15
#define CH 375     // NT*FI
#define PI 975

typedef __attribute__((ext_vector_type(8))) short v8s;
typedef __attribute__((ext_vector_type(4))) float v4f;

__device__ __forceinline__ unsigned short f2bfu(float v) {
  __hip_bfloat16 h = __float2bfloat16(v);
  return *reinterpret_cast<unsigned short*>(&h);
}
__device__ __forceinline__ float bfu2f(unsigned short u) {
  return __uint_as_float(((unsigned)u) << 16);
}

// ---------------- prep ----------------
__global__ void k_gather_x(const int* __restrict__ xidx, const float* __restrict__ emb,
                           float* __restrict__ x) {
  int i = blockIdx.x * 256 + threadIdx.x;
  if (i < NN * FI) {
    int n = i / FI, f = i - n * FI;
    x[i] = emb[xidx[n] * FI + f];
  }
}

__global__ void k_count(const int* __restrict__ dst, int* __restrict__ deg) {
  int e = blockIdx.x * 256 + threadIdx.x;
  if (e < NE) atomicAdd(&deg[dst[e]], 1);
}

__global__ void k_scan(const int* __restrict__ deg, int* __restrict__ off,
                       int* __restrict__ cur) {
  __shared__ int buf[1024];
  __shared__ int carry;
  int tx = threadIdx.x;
  if (tx == 0) carry = 0;
  __syncthreads();
  for (int base = 0; base < NN; base += 1024) {
    int i = base + tx;
    int v = (i < NN) ? deg[i] : 0;
    buf[tx] = v;
    __syncthreads();
    for (int o = 1; o < 1024; o <<= 1) {
      int t = (tx >= o) ? buf[tx - o] : 0;
      __syncthreads();
      buf[tx] += t;
      __syncthreads();
    }
    if (i < NN) { int ex = carry + buf[tx] - v; off[i] = ex; cur[i] = ex; }
    __syncthreads();
    if (tx == 0) carry += buf[1023];
    __syncthreads();
  }
  if (tx == 0) off[NN] = carry;
}

__global__ void k_fill(const int* __restrict__ srcp, const int* __restrict__ dstp,
                       const int* __restrict__ attr, int* __restrict__ cur,
                       int2* __restrict__ csr) {
  int e = blockIdx.x * 256 + threadIdx.x;
  if (e < NE) {
    int pos = atomicAdd(&cur[dstp[e]], 1);
    csr[pos] = make_int2(srcp[e], attr[e]);
  }
}

__global__ void k_logsum(const int* __restrict__ deg, float* __restrict__ avglog) {
  __shared__ float red[1024];
  float s = 0.f;
  for (int i = threadIdx.x; i < NN; i += 1024) s += logf((float)deg[i] + 1.f);
  red[threadIdx.x] = s;
  __syncthreads();
  for (int o = 512; o > 0; o >>= 1) {
    if (threadIdx.x < o) red[threadIdx.x] += red[threadIdx.x + o];
    __syncthreads();
  }
  if (threadIdx.x == 0) avglog[0] = red[0] / (float)NN;
}

__global__ void k_scalers(const int* __restrict__ deg, const float* __restrict__ avglog,
                          float* __restrict__ amp, float* __restrict__ att,
                          float* __restrict__ inv) {
  int i = blockIdx.x * 256 + threadIdx.x;
  if (i < NN) {
    float dc = fmaxf((float)deg[i], 1.f);
    float ld = logf(dc + 1.f);
    float av = avglog[0];
    amp[i] = ld / av;
    att[i] = av / ld;
    inv[i] = 1.f / dc;
  }
}

// te[l,a,:] = edge_emb[a]@W_edge[l]+b_edge[l]   (fp32)
__global__ void k_table_e(const float* __restrict__ eemb, const float* __restrict__ W_edge,
                          const float* __restrict__ b_edge, float* __restrict__ te) {
  int la = blockIdx.x;               // l*100+a
  int l = la / 100, a = la - l * 100;
  int f = threadIdx.x;
  if (f < FI) {
    float acc = b_edge[l * FI + f];
    for (int j = 0; j < 50; ++j)
      acc = fmaf(eemb[a * 50 + j], W_edge[(l * 50 + j) * FI + f], acc);
    te[la * FI + f] = acc;
  }
}

// tm_bf[l,a,c] (stride 384, bf16) = te[l,a]@W_pre[l,t,150:225,f] + b_pre[l,t,f]
__global__ void k_tbl_m(const float* __restrict__ te, const float* __restrict__ W_pre,
                        const float* __restrict__ b_pre, unsigned short* __restrict__ tm) {
  int la = blockIdx.x;
  int l = la / 100;
  int c = threadIdx.x;               // 0..383
  float acc = 0.f;
  if (c < CH) {
    int t = c / FI, f = c - t * FI;
    acc = b_pre[(l * NT + t) * FI + f];
    const float* ter = te + la * FI;
    for (int k = 0; k < FI; ++k)
      acc = fmaf(ter[k], W_pre[((size_t)(l * NT + t) * 225 + 150 + k) * FI + f], acc);
  }
  if (c < 384) tm[(size_t)la * 384 + c] = f2bfu(acc);
}

// WAs[l,k,c] = W_pre src rows (fp32): W_pre[l, t, 75+k, f], c = t*75+f
__global__ void k_repack_WAs(const float* __restrict__ W_pre, float* __restrict__ WAs) {
  int i = blockIdx.x * 256 + threadIdx.x;
  if (i < 2 * FI * CH) {
    int c = i % CH;
    int k = (i / CH) % FI;
    int l = i / (CH * FI);
    int t = c / FI, f = c - t * FI;
    WAs[i] = W_pre[((size_t)(l * NT + t) * 225 + FI + k) * FI + f];
  }
}

// V[((l*5+t)*3+g)*75 + j][16f] = sum_q W_pre_dst[l,t,j,q] * (W_post mean+min+max rows, g)
__global__ void k_make_V(const float* __restrict__ W_pre, const float* __restrict__ W_post,
                         float* __restrict__ V) {
  int bid = blockIdx.x;              // (l*5+t)*3 + g
  int g = bid % 3;
  int lt = bid / 3;
  __shared__ float S[FI * 16];
  int tid = threadIdx.x;
  for (int idx = tid; idx < FI * 16; idx += 128) {
    int q = idx >> 4, f = idx & 15;
    float v = 0.f;
    if (f < FO) {
      const float* wb = W_post + (size_t)lt * PI * FO;
      int rowb = FI + g * 300 + q;
      v = wb[rowb * FO + f] + wb[(rowb + FI) * FO + f] + wb[(rowb + 2 * FI) * FO + f];
    }
    S[idx] = v;
  }
  __syncthreads();
  for (int idx = tid; idx < FI * 16; idx += 128) {
    int j = idx >> 4, f = idx & 15;
    float acc = 0.f;
    const float* wr = W_pre + ((size_t)lt * 225 + j) * FI;   // dst row j
    for (int q = 0; q < FI; ++q) acc = fmaf(wr[q], S[q * 16 + f], acc);
    V[((size_t)bid * FI + j) * 16 + f] = acc;
  }
}

// B-operand pack for mfma_f32_16x16x32_bf16.
// Wc_t rows (K=480): 0:300 agg (a*75+ch), 300:320 zero, 320:395 V_g (x*hi),
// 395:470 self (g==0 only), 470:480 zero. Layout:
// Bpack[((((l*5+t)*3+g)*15+kb)*64+lane)*8+j] = Wc[k=kb*32+(lane>>4)*8+j][f=lane&15]
__global__ void k_pack_B(const float* __restrict__ W_post, const float* __restrict__ V,
                         unsigned short* __restrict__ Bp) {
  int i = blockIdx.x * 256 + threadIdx.x;
  if (i >= 230400) return;
  int j = i & 7;
  int lane = (i >> 3) & 63;
  int rem = i >> 9;
  int kb = rem % 15; rem /= 15;
  int g = rem % 3; rem /= 3;
  int t = rem % 5;
  int l = rem / 5;
  int k = kb * 32 + (lane >> 4) * 8 + j;
  int f = lane & 15;
  float w = 0.f;
  if (f < FO) {
    int lt = l * NT + t;
    if (k < 300) {
      int a = k / 75, ch = k - a * 75;
      w = W_post[((size_t)lt * PI + FI + g * 300 + a * 75 + ch) * FO + f];
    } else if (k >= 320 && k < 395) {
      w = V[(((size_t)(lt * 3 + g)) * FI + (k - 320)) * 16 + f];
    } else if (k >= 395 && k < 470 && g == 0) {
      w = W_post[((size_t)lt * PI + (k - 395)) * FO + f];
    }
  }
  Bp[i] = f2bfu(w);
}

// bc[l*76+g] = b_post_flat[l]@W_lin[l] + b_lin[l]
__global__ void k_bias_comb(const float* __restrict__ b_post, const float* __restrict__ W_lin,
                            const float* __restrict__ b_lin, float* __restrict__ bc) {
  int l = blockIdx.x;
  int g = threadIdx.x;
  if (g < FI) {
    float acc = b_lin[l * FI + g];
    for (int j = 0; j < FI; ++j)
      acc = fmaf(b_post[l * FI + j], W_lin[(l * FI + j) * FI + g], acc);
    bc[l * 76 + g] = acc;
  }
}

// ---------------- per-layer ----------------
// xs_bf[n, 0:384] (bf16) = x[n] @ W_pre_src, cols 375:384 zero
__global__ __launch_bounds__(256) void k_gemm_xs(const float* __restrict__ x,
                                                 const float* __restrict__ WsL,
                                                 unsigned short* __restrict__ xsb) {
  __shared__ float Xs[64 * FI];
  __shared__ float Ws[FI * 128];
  int n0 = blockIdx.x * 64;
  int c0 = blockIdx.y * 128;
  int tid = threadIdx.x;
  for (int i = tid; i < 64 * FI; i += 256) {
    int n = n0 + i / FI;
    Xs[i] = (n < NN) ? x[(size_t)n0 * FI + i] : 0.f;
  }
  for (int i = tid; i < FI * 128; i += 256) {
    int k = i >> 7, cc = i & 127;
    Ws[i] = (c0 + cc < CH) ? WsL[k * CH + c0 + cc] : 0.f;
  }
  __syncthreads();
  int tx = tid & 31, ty = tid >> 5;  // ty 0..7
  float acc[8][4];
#pragma unroll
  for (int i = 0; i < 8; ++i)
#pragma unroll
    for (int j = 0; j < 4; ++j) acc[i][j] = 0.f;
  for (int k = 0; k < FI; ++k) {
    float a_[8], b_[4];
#pragma unroll
    for (int i = 0; i < 8; ++i) a_[i] = Xs[(ty + 8 * i) * FI + k];
#pragma unroll
    for (int j = 0; j < 4; ++j) b_[j] = Ws[k * 128 + tx + 32 * j];
#pragma unroll
    for (int i = 0; i < 8; ++i)
#pragma unroll
      for (int j = 0; j < 4; ++j) acc[i][j] = fmaf(a_[i], b_[j], acc[i][j]);
  }
#pragma unroll
  for (int i = 0; i < 8; ++i) {
    int n = n0 + ty + 8 * i;
    if (n < NN) {
#pragma unroll
      for (int j = 0; j < 4; ++j) {
        int c = c0 + tx + 32 * j;
        if (c < 384) xsb[(size_t)n * 384 + c] = f2bfu(acc[i][j]);
      }
    }
  }
}

// xh[r, 0:160] bf16: [x*has_in | x | zeros]
__global__ void k_make_xh(int n0, int cn, const float* __restrict__ x,
                          const int* __restrict__ deg, unsigned short* __restrict__ xh) {
  int i = blockIdx.x * 256 + threadIdx.x;
  if (i < cn * 160) {
    int r = i / 160, k = i - r * 160;
    int n = n0 + r;
    float v = 0.f;
    if (k < FI) v = x[(size_t)n * FI + k] * ((deg[n] > 0) ? 1.f : 0.f);
    else if (k < 150) v = x[(size_t)n * FI + k - FI];
    xh[(size_t)r * 160 + k] = f2bfu(v);
  }
}

// per-node stats of z = xs[src] + tm[attr]; output AggA bf16 tower-major:
// aggA[r][t*320 + a*75 + ch], a = mean,min,max,std; cols 300:320 per tower zero.
__global__ __launch_bounds__(128) void k_aggregate(int n0,
    const unsigned short* __restrict__ xs, const int2* __restrict__ csr,
    const int* __restrict__ off, const float* __restrict__ inv_deg,
    const unsigned short* __restrict__ tm, unsigned short* __restrict__ aggA) {
  int n = n0 + blockIdx.x;
  int tx = threadIdx.x;
  unsigned short* arow = aggA + (size_t)blockIdx.x * 1600;
  if (tx >= 96) {
    for (int pp = tx - 96; pp < 100; pp += 32) {
      int t = pp / 20, cc = pp - t * 20;
      arow[t * 320 + 300 + cc] = 0;
    }
    return;
  }
  int o0 = off[n], o1 = off[n + 1];
  int c0 = tx * 4;
  float s[4] = {0, 0, 0, 0}, q[4] = {0, 0, 0, 0};
  float mn[4], mx[4];
#pragma unroll
  for (int j = 0; j < 4; ++j) { mn[j] = INFINITY; mx[j] = -INFINITY; }
  for (int i = o0; i < o1; ++i) {
    int2 e = csr[i];
    unsigned long long xv = *(const unsigned long long*)(xs + (size_t)e.x * 384 + c0);
    unsigned long long tv = *(const unsigned long long*)(tm + (size_t)e.y * 384 + c0);
#pragma unroll
    for (int j = 0; j < 4; ++j) {
      float z = bfu2f((unsigned short)(xv >> (16 * j))) +
                bfu2f((unsigned short)(tv >> (16 * j)));
      s[j] += z;
      q[j] = fmaf(z, z, q[j]);
      mn[j] = fminf(mn[j], z);
      mx[j] = fmaxf(mx[j], z);
    }
  }
  float inv = inv_deg[n];
  bool empty = (o1 == o0);
#pragma unroll
  for (int j = 0; j < 4; ++j) {
    int c = c0 + j;
    if (c < CH) {
      float me = s[j] * inv;
      float sd = sqrtf(fmaxf(q[j] * inv - me * me, 0.f) + 1e-5f);
      float mnv = empty ? 0.f : mn[j];
      float mxv = empty ? 0.f : mx[j];
      int t = c / 75, ch = c - t * 75;
      unsigned short* b = arow + t * 320;
      b[ch] = f2bfu(me);
      b[75 + ch] = f2bfu(mnv);
      b[150 + ch] = f2bfu(mxv);
      b[225 + ch] = f2bfu(sd);
    }
  }
}

// MFMA post GEMM: per tower, S_g[node,16] = A[node,480]@Wc_g; combine with scalers -> z
__global__ __launch_bounds__(128) void k_mfma_post(int n0, int nend,
    const unsigned short* __restrict__ aggA, const unsigned short* __restrict__ xh,
    const unsigned short* __restrict__ Bp, const float* __restrict__ amp,
    const float* __restrict__ att, float* __restrict__ z) {
  int t = blockIdx.y;
  int lane = threadIdx.x & 63;
  int wv = threadIdx.x >> 6;         // 0..1 (M-halves of 32-node tile)
  int m16 = lane & 15, quad = lane >> 4;
  int relA = blockIdx.x * 32 + wv * 16 + m16;
  const unsigned short* arow = aggA + (size_t)relA * 1600 + t * 320 + quad * 8;
  const unsigned short* xrow = xh + (size_t)relA * 160 + quad * 8;
  const unsigned short* bp = Bp + ((size_t)t * 3 * 15 * 64) * 8 + lane * 8;
  v4f a0 = {0.f, 0.f, 0.f, 0.f}, a1 = a0, a2 = a0;
#pragma unroll
  for (int kb = 0; kb < 15; ++kb) {
    v8s av = *(const v8s*)((kb < 10) ? (arow + kb * 32) : (xrow + (kb - 10) * 32));
    const unsigned short* bb = bp + (size_t)kb * 512;
    v8s b0 = *(const v8s*)(bb);
    v8s b1 = *(const v8s*)(bb + 15 * 512);
    v8s b2 = *(const v8s*)(bb + 30 * 512);
    a0 = __builtin_amdgcn_mfma_f32_16x16x32_bf16(av, b0, a0, 0, 0, 0);
    a1 = __builtin_amdgcn_mfma_f32_16x16x32_bf16(av, b1, a1, 0, 0, 0);
    a2 = __builtin_amdgcn_mfma_f32_16x16x32_bf16(av, b2, a2, 0, 0, 0);
  }
  // D: m = quad*4 + r, n(f) = lane&15
  int f = m16;
  if (f < FO) {
    int relD0 = blockIdx.x * 32 + wv * 16 + quad * 4;
#pragma unroll
    for (int r = 0; r < 4; ++r) {
      int nd = n0 + relD0 + r;
      if (nd < nend) {
        float zz = a0[r] + amp[nd] * a1[r] + att[nd] * a2[r];
        z[(size_t)nd * FI + t * FO + f] = zz;
      }
    }
  }
}

// y = z @ W_lin + bc (in-place over z) + BN partial sums
__global__ __launch_bounds__(256) void k_gemm75(const float* __restrict__ zin,
    const float* __restrict__ Wl, const float* __restrict__ bcL,
    float* __restrict__ yout, float* __restrict__ bnsum) {
  __shared__ float Zs[64 * FI];      // 19.2 KB
  __shared__ float Ws[FI * 76];      // 22.8 KB
  __shared__ float ysum[FI], ysq[FI];
  int tid = threadIdx.x;
  int n0 = blockIdx.x * 64;
  for (int i = tid; i < 64 * FI; i += 256) {
    int n = n0 + i / FI;
    Zs[i] = (n < NN) ? zin[(size_t)n0 * FI + i] : 0.f;
  }
  for (int i = tid; i < FI * FI; i += 256) {
    int k = i / FI, f = i - k * FI;
    Ws[k * 76 + f] = Wl[i];
  }
  if (tid < FI) { ysum[tid] = 0.f; ysq[tid] = 0.f; }
  __syncthreads();
  int nl = tid >> 2, fg = tid & 3;
  int f0 = fg * 19;
  float acc[19];
#pragma unroll
  for (int i = 0; i < 19; ++i) acc[i] = bcL[f0 + i];   // bc alloc padded to 76/layer
  for (int k = 0; k < FI; ++k) {
    float a = Zs[nl * FI + k];
#pragma unroll
    for (int i = 0; i < 19; ++i) acc[i] = fmaf(a, Ws[k * 76 + f0 + i], acc[i]);
  }
  int n = n0 + nl;
  if (n < NN) {
#pragma unroll
    for (int i = 0; i < 19; ++i) {
      int f = f0 + i;
      if (f < FI) {
        float v = acc[i];
        yout[(size_t)n * FI + f] = v;
        atomicAdd(&ysum[f], v);
        atomicAdd(&ysq[f], v * v);
      }
    }
  }
  __syncthreads();
  if (tid < FI) {
    atomicAdd(&bnsum[tid], ysum[tid]);
    atomicAdd(&bnsum[FI + tid], ysq[tid]);
  }
}

__global__ void k_bnfin(const float* __restrict__ bnsum, const float* __restrict__ gamL,
                        const float* __restrict__ betL, float* __restrict__ bnsc) {
  int f = threadIdx.x;
  if (f < FI) {
    float mu = bnsum[f] / (float)NN;
    float var = bnsum[FI + f] / (float)NN - mu * mu;
    float scl = gamL[f] * rsqrtf(var + 1e-5f);
    bnsc[f] = scl;
    bnsc[FI + f] = betL[f] - mu * scl;
  }
}

__global__ void k_bnapply(const float* __restrict__ y, const float* __restrict__ bnsc,
                          float* __restrict__ xo) {
  int i = blockIdx.x * 256 + threadIdx.x;
  if (i < NN * FI) {
    int f = i % FI;
    xo[i] = fmaxf(fmaf(y[i], bnsc[f], bnsc[FI + f]), 0.f);
  }
}

// ---------------- readout ----------------
__global__ void k_pool(const float* __restrict__ x, const int* __restrict__ batch,
                       float* __restrict__ pooled) {
  int i = blockIdx.x * 256 + threadIdx.x;
  if (i < NN * FI) {
    int n = i / FI, f = i - n * FI;
    atomicAdd(&pooled[batch[n] * FI + f], x[i]);
  }
}

__global__ void k_head(const float* __restrict__ pooled, const float* __restrict__ W1,
                       const float* __restrict__ b1, const float* __restrict__ W2,
                       const float* __restrict__ b2, const float* __restrict__ W3,
                       const float* __restrict__ b3, float* __restrict__ out) {
  __shared__ float p[FI], h1[50], h2[25];
  int g = blockIdx.x, t = threadIdx.x;
  for (int i = t; i < FI; i += 64) p[i] = pooled[g * FI + i];
  __syncthreads();
  if (t < 50) {
    float a = b1[t];
    for (int j = 0; j < FI; ++j) a = fmaf(p[j], W1[j * 50 + t], a);
    h1[t] = fmaxf(a, 0.f);
  }
  __syncthreads();
  if (t < 25) {
    float a = b2[t];
    for (int j = 0; j < 50; ++j) a = fmaf(h1[j], W2[j * 25 + t], a);
    h2[t] = fmaxf(a, 0.f);
  }
  __syncthreads();
  if (t == 0) {
    float a = b3[0];
    for (int j = 0; j < 25; ++j) a = fmaf(h2[j], W3[j], a);
    out[g] = a;
  }
}

extern "C" void kernel_launch(void* const* d_in, const int* in_sizes, int n_in,
                              void* d_out, int out_size, void* d_ws, size_t ws_size,
                              hipStream_t stream) {
  const int* x_idx = (const int*)d_in[0];
  const int* eidx  = (const int*)d_in[1];
  const int* srcp  = eidx;
  const int* dstp  = eidx + NE;
  const int* eattr = (const int*)d_in[2];
  const int* batch = (const int*)d_in[3];
  const float* node_emb = (const float*)d_in[4];
  const float* edge_emb = (const float*)d_in[5];
  const float* W_edge = (const float*)d_in[6];
  const float* b_edge = (const float*)d_in[7];
  const float* W_pre  = (const float*)d_in[8];
  const float* b_pre  = (const float*)d_in[9];
  const float* W_post = (const float*)d_in[10];
  const float* b_post = (const float*)d_in[11];
  const float* W_lin  = (const float*)d_in[12];
  const float* b_lin  = (const float*)d_in[13];
  const float* gam = (const float*)d_in[14];
  const float* bet = (const float*)d_in[15];
  const float* W1 = (const float*)d_in[16];
  const float* b1 = (const float*)d_in[17];
  const float* W2 = (const float*)d_in[18];
  const float* b2 = (const float*)d_in[19];
  const float* W3 = (const float*)d_in[20];
  const float* b3 = (const float*)d_in[21];

  char* p = (char*)d_ws;
  auto alloc = [&](size_t b) -> char* {
    char* r = p;
    p += (b + 255) & ~(size_t)255;
    return r;
  };
  float* x_a   = (float*)alloc((size_t)NN * FI * 4);
  float* x_b   = (float*)alloc((size_t)NN * FI * 4);
  unsigned short* xs_bf = (unsigned short*)alloc((size_t)NN * 384 * 2);
  float* z     = (float*)alloc((size_t)NN * FI * 4);
  float* te    = (float*)alloc(2 * 100 * FI * 4);
  unsigned short* tm_bf = (unsigned short*)alloc((size_t)2 * 100 * 384 * 2);
  float* WAs   = (float*)alloc((size_t)2 * FI * CH * 4);
  float* V     = (float*)alloc((size_t)2 * NT * 3 * FI * 16 * 4);
  unsigned short* Bpk = (unsigned short*)alloc((size_t)230400 * 2);
  float* bc    = (float*)alloc(2 * 76 * 4);
  float* ampv  = (float*)alloc((size_t)NN * 4);
  float* attv  = (float*)alloc((size_t)NN * 4);
  float* invv  = (float*)alloc((size_t)NN * 4);
  float* avglog = (float*)alloc(256);
  float* bnsum = (float*)alloc(2 * FI * 4);
  float* bnsc  = (float*)alloc(2 * FI * 4);
  float* pooled = (float*)alloc((size_t)NG * FI * 4);
  int* deg = (int*)alloc((size_t)NN * 4);
  int* off = (int*)alloc((size_t)(NN + 1) * 4);
  int* cur = (int*)alloc((size_t)NN * 4);
  int2* csr = (int2*)alloc((size_t)NE * 8);
  size_t used = (size_t)(p - (char*)d_ws);
  int chunkN = NN;
  while (chunkN > 2500 &&
         used + (size_t)((chunkN + 31) & ~31) * 1760 * 2 + (1 << 20) > ws_size)
    chunkN >>= 1;
  int rows = (chunkN + 31) & ~31;
  unsigned short* aggA = (unsigned short*)alloc((size_t)rows * 1600 * 2);
  unsigned short* xh   = (unsigned short*)alloc((size_t)rows * 160 * 2);

  hipMemsetAsync(deg, 0, (size_t)NN * 4, stream);
  hipMemsetAsync(pooled, 0, (size_t)NG * FI * 4, stream);

  k_gather_x<<<(NN * FI + 255) / 256, 256, 0, stream>>>(x_idx, node_emb, x_a);
  k_count<<<(NE + 255) / 256, 256, 0, stream>>>(dstp, deg);
  k_scan<<<1, 1024, 0, stream>>>(deg, off, cur);
  k_fill<<<(NE + 255) / 256, 256, 0, stream>>>(srcp, dstp, eattr, cur, csr);
  k_logsum<<<1, 1024, 0, stream>>>(deg, avglog);
  k_scalers<<<(NN + 255) / 256, 256, 0, stream>>>(deg, avglog, ampv, attv, invv);
  k_table_e<<<200, 128, 0, stream>>>(edge_emb, W_edge, b_edge, te);
  k_tbl_m<<<200, 384, 0, stream>>>(te, W_pre, b_pre, tm_bf);
  k_repack_WAs<<<(2 * FI * CH + 255) / 256, 256, 0, stream>>>(W_pre, WAs);
  k_make_V<<<2 * NT * 3, 128, 0, stream>>>(W_pre, W_post, V);
  k_pack_B<<<(230400 + 255) / 256, 256, 0, stream>>>(W_post, V, Bpk);
  k_bias_comb<<<2, 128, 0, stream>>>(b_post, W_lin, b_lin, bc);

  for (int l = 0; l < 2; ++l) {
    const float* xin = (l == 0) ? x_a : x_b;
    float* xout = (l == 0) ? x_b : x_a;
    k_gemm_xs<<<dim3(313, 3), 256, 0, stream>>>(xin, WAs + (size_t)l * FI * CH, xs_bf);
    for (int n0 = 0; n0 < NN; n0 += chunkN) {
      int cn = (NN - n0 < chunkN) ? (NN - n0) : chunkN;
      k_make_xh<<<(cn * 160 + 255) / 256, 256, 0, stream>>>(n0, cn, xin, deg, xh);
      k_aggregate<<<cn, 128, 0, stream>>>(n0, xs_bf, csr, off, invv,
                                          tm_bf + (size_t)l * 100 * 384, aggA);
      k_mfma_post<<<dim3((cn + 31) / 32, 5), 128, 0, stream>>>(
          n0, n0 + cn, aggA, xh, Bpk + (size_t)l * 115200, ampv, attv, z);
    }
    hipMemsetAsync(bnsum, 0, 2 * FI * 4, stream);
    k_gemm75<<<313, 256, 0, stream>>>(z, W_lin + (size_t)l * FI * FI, bc + l * 76,
                                      z, bnsum);
    k_bnfin<<<1, 128, 0, stream>>>(bnsum, gam + l * FI, bet + l * FI, bnsc);
    k_bnapply<<<(NN * FI + 255) / 256, 256, 0, stream>>>(z, bnsc, xout);
  }

  k_pool<<<(NN * FI + 255) / 256, 256, 0, stream>>>(x_a, batch, pooled);
  k_head<<<NG, 64, 0, stream>>>(pooled, W1, b1, W2, b2, W3, b3, (float*)d_out);
}

// Round 5
// 631.988 us; speedup vs baseline: 2.1918x; 1.0316x over previous
//
#include <hip/hip_runtime.h>
#include <hip/hip_bf16.h>
#include <math.h>

#define NN 20000
#define NE 320000
#define NG 200
#define FI 75
#define NT 5
#define FO 15
#define CH 375     // NT*FI
#define PI 975

typedef __attribute__((ext_vector_type(8))) short v8s;
typedef __attribute__((ext_vector_type(4))) float v4f;

__device__ __forceinline__ unsigned short f2bfu(float v) {
  __hip_bfloat16 h = __float2bfloat16(v);
  return *reinterpret_cast<unsigned short*>(&h);
}
__device__ __forceinline__ float bfu2f(unsigned short u) {
  return __uint_as_float(((unsigned)u) << 16);
}
__device__ __forceinline__ float uif(unsigned u) { return __uint_as_float(u); }

// ---------------- prep ----------------
__global__ void k_gather_x(const int* __restrict__ xidx, const float* __restrict__ emb,
                           float* __restrict__ x) {
  int i = blockIdx.x * 256 + threadIdx.x;
  if (i < NN * FI) {
    int n = i / FI, f = i - n * FI;
    x[i] = emb[xidx[n] * FI + f];
  }
}

__global__ void k_count(const int* __restrict__ dst, int* __restrict__ deg) {
  int e = blockIdx.x * 256 + threadIdx.x;
  if (e < NE) atomicAdd(&deg[dst[e]], 1);
}

// single-pass scan: 1024 threads x 20 elements each
__global__ void k_scan(const int* __restrict__ deg, int* __restrict__ off,
                       int* __restrict__ cur) {
  __shared__ int wsum[16];
  int t = threadIdx.x;
  int base = t * 20;
  int loc[20];
  int s = 0;
#pragma unroll
  for (int j = 0; j < 20; ++j) {
    int i = base + j;
    int v = (i < NN) ? deg[i] : 0;
    loc[j] = s;
    s += v;
  }
  int lane = t & 63, w = t >> 6;
  int inc = s;
  for (int o = 1; o < 64; o <<= 1) {
    int u = __shfl_up(inc, o, 64);
    if (lane >= o) inc += u;
  }
  if (lane == 63) wsum[w] = inc;
  __syncthreads();
  if (t == 0) {
    int a = 0;
#pragma unroll
    for (int k = 0; k < 16; ++k) { int v = wsum[k]; wsum[k] = a; a += v; }
  }
  __syncthreads();
  int tex = wsum[w] + inc - s;   // exclusive prefix for this thread's segment
#pragma unroll
  for (int j = 0; j < 20; ++j) {
    int i = base + j;
    if (i < NN) { int e = tex + loc[j]; off[i] = e; cur[i] = e; }
  }
  if (t == 1023) off[NN] = tex + s;
}

__global__ void k_fill(const int* __restrict__ srcp, const int* __restrict__ dstp,
                       const int* __restrict__ attr, int* __restrict__ cur,
                       int2* __restrict__ csr) {
  int e = blockIdx.x * 256 + threadIdx.x;
  if (e < NE) {
    int pos = atomicAdd(&cur[dstp[e]], 1);
    csr[pos] = make_int2(srcp[e], attr[e]);
  }
}

__global__ void k_logsum(const int* __restrict__ deg, float* __restrict__ avglog) {
  __shared__ float red[1024];
  float s = 0.f;
  for (int i = threadIdx.x; i < NN; i += 1024) s += logf((float)deg[i] + 1.f);
  red[threadIdx.x] = s;
  __syncthreads();
  for (int o = 512; o > 0; o >>= 1) {
    if (threadIdx.x < o) red[threadIdx.x] += red[threadIdx.x + o];
    __syncthreads();
  }
  if (threadIdx.x == 0) avglog[0] = red[0] / (float)NN;
}

__global__ void k_scalers(const int* __restrict__ deg, const float* __restrict__ avglog,
                          float* __restrict__ amp, float* __restrict__ att,
                          float* __restrict__ inv) {
  int i = blockIdx.x * 256 + threadIdx.x;
  if (i < NN) {
    float dc = fmaxf((float)deg[i], 1.f);
    float ld = logf(dc + 1.f);
    float av = avglog[0];
    amp[i] = ld / av;
    att[i] = av / ld;
    inv[i] = 1.f / dc;
  }
}

// te[l,a,:] = edge_emb[a]@W_edge[l]+b_edge[l]   (fp32)
__global__ void k_table_e(const float* __restrict__ eemb, const float* __restrict__ W_edge,
                          const float* __restrict__ b_edge, float* __restrict__ te) {
  int la = blockIdx.x;               // l*100+a
  int l = la / 100, a = la - l * 100;
  int f = threadIdx.x;
  if (f < FI) {
    float acc = b_edge[l * FI + f];
    for (int j = 0; j < 50; ++j)
      acc = fmaf(eemb[a * 50 + j], W_edge[(l * 50 + j) * FI + f], acc);
    te[la * FI + f] = acc;
  }
}

// tm_bf[l,a,c] (stride 384, bf16) = te[l,a]@W_pre[l,t,150:225,f] + b_pre[l,t,f]
__global__ void k_tbl_m(const float* __restrict__ te, const float* __restrict__ W_pre,
                        const float* __restrict__ b_pre, unsigned short* __restrict__ tm) {
  int la = blockIdx.x;
  int l = la / 100;
  int c = threadIdx.x;               // 0..383
  float acc = 0.f;
  if (c < CH) {
    int t = c / FI, f = c - t * FI;
    acc = b_pre[(l * NT + t) * FI + f];
    const float* ter = te + la * FI;
    for (int k = 0; k < FI; ++k)
      acc = fmaf(ter[k], W_pre[((size_t)(l * NT + t) * 225 + 150 + k) * FI + f], acc);
  }
  if (c < 384) tm[(size_t)la * 384 + c] = f2bfu(acc);
}

// WAs[l,k,c] = W_pre src rows (fp32): W_pre[l, t, 75+k, f], c = t*75+f
__global__ void k_repack_WAs(const float* __restrict__ W_pre, float* __restrict__ WAs) {
  int i = blockIdx.x * 256 + threadIdx.x;
  if (i < 2 * FI * CH) {
    int c = i % CH;
    int k = (i / CH) % FI;
    int l = i / (CH * FI);
    int t = c / FI, f = c - t * FI;
    WAs[i] = W_pre[((size_t)(l * NT + t) * 225 + FI + k) * FI + f];
  }
}

// V[((l*5+t)*3+g)*75 + j][16f] = sum_q W_pre_dst[l,t,j,q] * (W_post mean+min+max rows, g)
__global__ void k_make_V(const float* __restrict__ W_pre, const float* __restrict__ W_post,
                         float* __restrict__ V) {
  int bid = blockIdx.x;              // (l*5+t)*3 + g
  int g = bid % 3;
  int lt = bid / 3;
  __shared__ float S[FI * 16];
  int tid = threadIdx.x;
  for (int idx = tid; idx < FI * 16; idx += 128) {
    int q = idx >> 4, f = idx & 15;
    float v = 0.f;
    if (f < FO) {
      const float* wb = W_post + (size_t)lt * PI * FO;
      int rowb = FI + g * 300 + q;
      v = wb[rowb * FO + f] + wb[(rowb + FI) * FO + f] + wb[(rowb + 2 * FI) * FO + f];
    }
    S[idx] = v;
  }
  __syncthreads();
  for (int idx = tid; idx < FI * 16; idx += 128) {
    int j = idx >> 4, f = idx & 15;
    float acc = 0.f;
    const float* wr = W_pre + ((size_t)lt * 225 + j) * FI;   // dst row j
    for (int q = 0; q < FI; ++q) acc = fmaf(wr[q], S[q * 16 + f], acc);
    V[((size_t)bid * FI + j) * 16 + f] = acc;
  }
}

// B-operand pack for mfma_f32_16x16x32_bf16.
// Wc_t rows (K=480): 0:300 agg (a*75+ch), 300:320 zero, 320:395 V_g (x*hi),
// 395:470 self (g==0 only), 470:480 zero. Layout:
// Bpack[((((l*5+t)*3+g)*15+kb)*64+lane)*8+j] = Wc[k=kb*32+(lane>>4)*8+j][f=lane&15]
__global__ void k_pack_B(const float* __restrict__ W_post, const float* __restrict__ V,
                         unsigned short* __restrict__ Bp) {
  int i = blockIdx.x * 256 + threadIdx.x;
  if (i >= 230400) return;
  int j = i & 7;
  int lane = (i >> 3) & 63;
  int rem = i >> 9;
  int kb = rem % 15; rem /= 15;
  int g = rem % 3; rem /= 3;
  int t = rem % 5;
  int l = rem / 5;
  int k = kb * 32 + (lane >> 4) * 8 + j;
  int f = lane & 15;
  float w = 0.f;
  if (f < FO) {
    int lt = l * NT + t;
    if (k < 300) {
      int a = k / 75, ch = k - a * 75;
      w = W_post[((size_t)lt * PI + FI + g * 300 + a * 75 + ch) * FO + f];
    } else if (k >= 320 && k < 395) {
      w = V[(((size_t)(lt * 3 + g)) * FI + (k - 320)) * 16 + f];
    } else if (k >= 395 && k < 470 && g == 0) {
      w = W_post[((size_t)lt * PI + (k - 395)) * FO + f];
    }
  }
  Bp[i] = f2bfu(w);
}

// bc[l*76+g] = b_post_flat[l]@W_lin[l] + b_lin[l]
__global__ void k_bias_comb(const float* __restrict__ b_post, const float* __restrict__ W_lin,
                            const float* __restrict__ b_lin, float* __restrict__ bc) {
  int l = blockIdx.x;
  int g = threadIdx.x;
  if (g < FI) {
    float acc = b_lin[l * FI + g];
    for (int j = 0; j < FI; ++j)
      acc = fmaf(b_post[l * FI + j], W_lin[(l * FI + j) * FI + g], acc);
    bc[l * 76 + g] = acc;
  }
}

// ---------------- per-layer ----------------
// xs_bf[n, 0:384] (bf16) = x[n] @ W_pre_src, cols 375:384 zero
__global__ __launch_bounds__(256) void k_gemm_xs(const float* __restrict__ x,
                                                 const float* __restrict__ WsL,
                                                 unsigned short* __restrict__ xsb) {
  __shared__ float Xs[64 * FI];
  __shared__ float Ws[FI * 128];
  int n0 = blockIdx.x * 64;
  int c0 = blockIdx.y * 128;
  int tid = threadIdx.x;
  for (int i = tid; i < 64 * FI; i += 256) {
    int n = n0 + i / FI;
    Xs[i] = (n < NN) ? x[(size_t)n0 * FI + i] : 0.f;
  }
  for (int i = tid; i < FI * 128; i += 256) {
    int k = i >> 7, cc = i & 127;
    Ws[i] = (c0 + cc < CH) ? WsL[k * CH + c0 + cc] : 0.f;
  }
  __syncthreads();
  int tx = tid & 31, ty = tid >> 5;  // ty 0..7
  float acc[8][4];
#pragma unroll
  for (int i = 0; i < 8; ++i)
#pragma unroll
    for (int j = 0; j < 4; ++j) acc[i][j] = 0.f;
  for (int k = 0; k < FI; ++k) {
    float a_[8], b_[4];
#pragma unroll
    for (int i = 0; i < 8; ++i) a_[i] = Xs[(ty + 8 * i) * FI + k];
#pragma unroll
    for (int j = 0; j < 4; ++j) b_[j] = Ws[k * 128 + tx + 32 * j];
#pragma unroll
    for (int i = 0; i < 8; ++i)
#pragma unroll
      for (int j = 0; j < 4; ++j) acc[i][j] = fmaf(a_[i], b_[j], acc[i][j]);
  }
#pragma unroll
  for (int i = 0; i < 8; ++i) {
    int n = n0 + ty + 8 * i;
    if (n < NN) {
#pragma unroll
      for (int j = 0; j < 4; ++j) {
        int c = c0 + tx + 32 * j;
        if (c < 384) xsb[(size_t)n * 384 + c] = f2bfu(acc[i][j]);
      }
    }
  }
}

// xh[r, 0:160] bf16: [x*has_in | x | zeros]
__global__ void k_make_xh(int n0, int cn, const float* __restrict__ x,
                          const int* __restrict__ deg, unsigned short* __restrict__ xh) {
  int i = blockIdx.x * 256 + threadIdx.x;
  if (i < cn * 160) {
    int r = i / 160, k = i - r * 160;
    int n = n0 + r;
    float v = 0.f;
    if (k < FI) v = x[(size_t)n * FI + k] * ((deg[n] > 0) ? 1.f : 0.f);
    else if (k < 150) v = x[(size_t)n * FI + k - FI];
    xh[(size_t)r * 160 + k] = f2bfu(v);
  }
}

// per-node stats of z = xs[src] + tm[attr]; AggA bf16 tower-major:
// aggA[r][t*320 + a*75 + ch], a = mean,min,max,std; cols 300:320 per tower zero.
// 192 threads = 2 nodes/block, 96 lanes x 4ch each; edge loop unrolled x2.
__global__ __launch_bounds__(192) void k_aggregate(int n0, int cn,
    const unsigned short* __restrict__ xs, const int2* __restrict__ csr,
    const int* __restrict__ off, const float* __restrict__ inv_deg,
    const unsigned short* __restrict__ tm, unsigned short* __restrict__ aggA) {
  int tid = threadIdx.x;
  int half = tid / 96;
  int lane96 = tid - half * 96;
  int rel = blockIdx.x * 2 + half;
  if (rel >= cn) return;
  int n = n0 + rel;
  int c0 = lane96 * 4;
  unsigned short* arow = aggA + (size_t)rel * 1600;
  int o0 = off[n], o1 = off[n + 1];
  float s[4] = {0, 0, 0, 0}, q[4] = {0, 0, 0, 0};
  float mn[4], mx[4];
#pragma unroll
  for (int j = 0; j < 4; ++j) { mn[j] = INFINITY; mx[j] = -INFINITY; }

  auto proc = [&](uint2 xv, uint2 tv) {
    float z[4];
    z[0] = uif(xv.x << 16) + uif(tv.x << 16);
    z[1] = uif(xv.x & 0xffff0000u) + uif(tv.x & 0xffff0000u);
    z[2] = uif(xv.y << 16) + uif(tv.y << 16);
    z[3] = uif(xv.y & 0xffff0000u) + uif(tv.y & 0xffff0000u);
#pragma unroll
    for (int j = 0; j < 4; ++j) {
      s[j] += z[j];
      q[j] = fmaf(z[j], z[j], q[j]);
      mn[j] = fminf(mn[j], z[j]);
      mx[j] = fmaxf(mx[j], z[j]);
    }
  };

  int i = o0;
  for (; i + 2 <= o1; i += 2) {
    int2 ea = csr[i], eb = csr[i + 1];
    uint2 xa = *(const uint2*)(xs + (size_t)ea.x * 384 + c0);
    uint2 ta = *(const uint2*)(tm + (size_t)ea.y * 384 + c0);
    uint2 xb = *(const uint2*)(xs + (size_t)eb.x * 384 + c0);
    uint2 tb = *(const uint2*)(tm + (size_t)eb.y * 384 + c0);
    proc(xa, ta);
    proc(xb, tb);
  }
  if (i < o1) {
    int2 ea = csr[i];
    uint2 xa = *(const uint2*)(xs + (size_t)ea.x * 384 + c0);
    uint2 ta = *(const uint2*)(tm + (size_t)ea.y * 384 + c0);
    proc(xa, ta);
  }

  float inv = inv_deg[n];
  bool empty = (o1 == o0);
#pragma unroll
  for (int j = 0; j < 4; ++j) {
    int c = c0 + j;
    if (c < CH) {
      float me = s[j] * inv;
      float sd = sqrtf(fmaxf(q[j] * inv - me * me, 0.f) + 1e-5f);
      float mnv = empty ? 0.f : mn[j];
      float mxv = empty ? 0.f : mx[j];
      int t = c / 75, ch = c - t * 75;
      unsigned short* b = arow + t * 320;
      b[ch] = f2bfu(me);
      b[75 + ch] = f2bfu(mnv);
      b[150 + ch] = f2bfu(mxv);
      b[225 + ch] = f2bfu(sd);
    }
  }
  for (int pp = lane96; pp < 100; pp += 96) {
    int t = pp / 20, cc = pp - t * 20;
    arow[t * 320 + 300 + cc] = 0;
  }
}

// MFMA post GEMM: per tower, S_g[node,16] = A[node,480]@Wc_g; combine with scalers -> z
__global__ __launch_bounds__(128) void k_mfma_post(int n0, int nend,
    const unsigned short* __restrict__ aggA, const unsigned short* __restrict__ xh,
    const unsigned short* __restrict__ Bp, const float* __restrict__ amp,
    const float* __restrict__ att, float* __restrict__ z) {
  int t = blockIdx.y;
  int lane = threadIdx.x & 63;
  int wv = threadIdx.x >> 6;         // 0..1 (M-halves of 32-node tile)
  int m16 = lane & 15, quad = lane >> 4;
  int relA = blockIdx.x * 32 + wv * 16 + m16;
  const unsigned short* arow = aggA + (size_t)relA * 1600 + t * 320 + quad * 8;
  const unsigned short* xrow = xh + (size_t)relA * 160 + quad * 8;
  const unsigned short* bp = Bp + ((size_t)t * 3 * 15 * 64) * 8 + lane * 8;
  v4f a0 = {0.f, 0.f, 0.f, 0.f}, a1 = a0, a2 = a0;
#pragma unroll
  for (int kb = 0; kb < 15; ++kb) {
    v8s av = *(const v8s*)((kb < 10) ? (arow + kb * 32) : (xrow + (kb - 10) * 32));
    const unsigned short* bb = bp + (size_t)kb * 512;
    v8s b0 = *(const v8s*)(bb);
    v8s b1 = *(const v8s*)(bb + 15 * 512);
    v8s b2 = *(const v8s*)(bb + 30 * 512);
    a0 = __builtin_amdgcn_mfma_f32_16x16x32_bf16(av, b0, a0, 0, 0, 0);
    a1 = __builtin_amdgcn_mfma_f32_16x16x32_bf16(av, b1, a1, 0, 0, 0);
    a2 = __builtin_amdgcn_mfma_f32_16x16x32_bf16(av, b2, a2, 0, 0, 0);
  }
  // D: m = quad*4 + r, n(f) = lane&15
  int f = m16;
  if (f < FO) {
    int relD0 = blockIdx.x * 32 + wv * 16 + quad * 4;
#pragma unroll
    for (int r = 0; r < 4; ++r) {
      int nd = n0 + relD0 + r;
      if (nd < nend) {
        float zz = a0[r] + amp[nd] * a1[r] + att[nd] * a2[r];
        z[(size_t)nd * FI + t * FO + f] = zz;
      }
    }
  }
}

// y = z @ W_lin + bc (in-place over z) + BN partial sums
__global__ __launch_bounds__(256) void k_gemm75(const float* __restrict__ zin,
    const float* __restrict__ Wl, const float* __restrict__ bcL,
    float* __restrict__ yout, float* __restrict__ bnsum) {
  __shared__ float Zs[64 * FI];      // 19.2 KB
  __shared__ float Ws[FI * 76];      // 22.8 KB
  __shared__ float ysum[FI], ysq[FI];
  int tid = threadIdx.x;
  int n0 = blockIdx.x * 64;
  for (int i = tid; i < 64 * FI; i += 256) {
    int n = n0 + i / FI;
    Zs[i] = (n < NN) ? zin[(size_t)n0 * FI + i] : 0.f;
  }
  for (int i = tid; i < FI * FI; i += 256) {
    int k = i / FI, f = i - k * FI;
    Ws[k * 76 + f] = Wl[i];
  }
  if (tid < FI) { ysum[tid] = 0.f; ysq[tid] = 0.f; }
  __syncthreads();
  int nl = tid >> 2, fg = tid & 3;
  int f0 = fg * 19;
  float acc[19];
#pragma unroll
  for (int i = 0; i < 19; ++i) acc[i] = bcL[f0 + i];   // bc alloc padded to 76/layer
  for (int k = 0; k < FI; ++k) {
    float a = Zs[nl * FI + k];
#pragma unroll
    for (int i = 0; i < 19; ++i) acc[i] = fmaf(a, Ws[k * 76 + f0 + i], acc[i]);
  }
  int n = n0 + nl;
  if (n < NN) {
#pragma unroll
    for (int i = 0; i < 19; ++i) {
      int f = f0 + i;
      if (f < FI) {
        float v = acc[i];
        yout[(size_t)n * FI + f] = v;
        atomicAdd(&ysum[f], v);
        atomicAdd(&ysq[f], v * v);
      }
    }
  }
  __syncthreads();
  if (tid < FI) {
    atomicAdd(&bnsum[tid], ysum[tid]);
    atomicAdd(&bnsum[FI + tid], ysq[tid]);
  }
}

__global__ void k_bnfin(const float* __restrict__ bnsum, const float* __restrict__ gamL,
                        const float* __restrict__ betL, float* __restrict__ bnsc) {
  int f = threadIdx.x;
  if (f < FI) {
    float mu = bnsum[f] / (float)NN;
    float var = bnsum[FI + f] / (float)NN - mu * mu;
    float scl = gamL[f] * rsqrtf(var + 1e-5f);
    bnsc[f] = scl;
    bnsc[FI + f] = betL[f] - mu * scl;
  }
}

__global__ void k_bnapply(const float* __restrict__ y, const float* __restrict__ bnsc,
                          float* __restrict__ xo) {
  int i = blockIdx.x * 256 + threadIdx.x;
  if (i < NN * FI) {
    int f = i % FI;
    xo[i] = fmaxf(fmaf(y[i], bnsc[f], bnsc[FI + f]), 0.f);
  }
}

// ---------------- readout ----------------
__global__ void k_pool(const float* __restrict__ x, const int* __restrict__ batch,
                       float* __restrict__ pooled) {
  int i = blockIdx.x * 256 + threadIdx.x;
  if (i < NN * FI) {
    int n = i / FI, f = i - n * FI;
    atomicAdd(&pooled[batch[n] * FI + f], x[i]);
  }
}

__global__ void k_head(const float* __restrict__ pooled, const float* __restrict__ W1,
                       const float* __restrict__ b1, const float* __restrict__ W2,
                       const float* __restrict__ b2, const float* __restrict__ W3,
                       const float* __restrict__ b3, float* __restrict__ out) {
  __shared__ float p[FI], h1[50], h2[25];
  int g = blockIdx.x, t = threadIdx.x;
  for (int i = t; i < FI; i += 64) p[i] = pooled[g * FI + i];
  __syncthreads();
  if (t < 50) {
    float a = b1[t];
    for (int j = 0; j < FI; ++j) a = fmaf(p[j], W1[j * 50 + t], a);
    h1[t] = fmaxf(a, 0.f);
  }
  __syncthreads();
  if (t < 25) {
    float a = b2[t];
    for (int j = 0; j < 50; ++j) a = fmaf(h1[j], W2[j * 25 + t], a);
    h2[t] = fmaxf(a, 0.f);
  }
  __syncthreads();
  if (t == 0) {
    float a = b3[0];
    for (int j = 0; j < 25; ++j) a = fmaf(h2[j], W3[j], a);
    out[g] = a;
  }
}

extern "C" void kernel_launch(void* const* d_in, const int* in_sizes, int n_in,
                              void* d_out, int out_size, void* d_ws, size_t ws_size,
                              hipStream_t stream) {
  const int* x_idx = (const int*)d_in[0];
  const int* eidx  = (const int*)d_in[1];
  const int* srcp  = eidx;
  const int* dstp  = eidx + NE;
  const int* eattr = (const int*)d_in[2];
  const int* batch = (const int*)d_in[3];
  const float* node_emb = (const float*)d_in[4];
  const float* edge_emb = (const float*)d_in[5];
  const float* W_edge = (const float*)d_in[6];
  const float* b_edge = (const float*)d_in[7];
  const float* W_pre  = (const float*)d_in[8];
  const float* b_pre  = (const float*)d_in[9];
  const float* W_post = (const float*)d_in[10];
  const float* b_post = (const float*)d_in[11];
  const float* W_lin  = (const float*)d_in[12];
  const float* b_lin  = (const float*)d_in[13];
  const float* gam = (const float*)d_in[14];
  const float* bet = (const float*)d_in[15];
  const float* W1 = (const float*)d_in[16];
  const float* b1 = (const float*)d_in[17];
  const float* W2 = (const float*)d_in[18];
  const float* b2 = (const float*)d_in[19];
  const float* W3 = (const float*)d_in[20];
  const float* b3 = (const float*)d_in[21];

  char* p = (char*)d_ws;
  auto alloc = [&](size_t b) -> char* {
    char* r = p;
    p += (b + 255) & ~(size_t)255;
    return r;
  };
  float* x_a   = (float*)alloc((size_t)NN * FI * 4);
  float* x_b   = (float*)alloc((size_t)NN * FI * 4);
  unsigned short* xs_bf = (unsigned short*)alloc((size_t)NN * 384 * 2);
  float* z     = (float*)alloc((size_t)NN * FI * 4);
  float* te    = (float*)alloc(2 * 100 * FI * 4);
  unsigned short* tm_bf = (unsigned short*)alloc((size_t)2 * 100 * 384 * 2);
  float* WAs   = (float*)alloc((size_t)2 * FI * CH * 4);
  float* V     = (float*)alloc((size_t)2 * NT * 3 * FI * 16 * 4);
  unsigned short* Bpk = (unsigned short*)alloc((size_t)230400 * 2);
  float* bc    = (float*)alloc(2 * 76 * 4);
  float* ampv  = (float*)alloc((size_t)NN * 4);
  float* attv  = (float*)alloc((size_t)NN * 4);
  float* invv  = (float*)alloc((size_t)NN * 4);
  float* avglog = (float*)alloc(256);
  float* bnsum = (float*)alloc(2 * FI * 4);
  float* bnsc  = (float*)alloc(2 * FI * 4);
  float* pooled = (float*)alloc((size_t)NG * FI * 4);
  int* deg = (int*)alloc((size_t)NN * 4);
  int* off = (int*)alloc((size_t)(NN + 1) * 4);
  int* cur = (int*)alloc((size_t)NN * 4);
  int2* csr = (int2*)alloc((size_t)NE * 8);
  size_t used = (size_t)(p - (char*)d_ws);
  int chunkN = NN;
  while (chunkN > 2500 &&
         used + (size_t)((chunkN + 31) & ~31) * 1760 * 2 + (1 << 20) > ws_size)
    chunkN >>= 1;
  int rows = (chunkN + 31) & ~31;
  unsigned short* aggA = (unsigned short*)alloc((size_t)rows * 1600 * 2);
  unsigned short* xh   = (unsigned short*)alloc((size_t)rows * 160 * 2);

  hipMemsetAsync(deg, 0, (size_t)NN * 4, stream);
  hipMemsetAsync(pooled, 0, (size_t)NG * FI * 4, stream);

  k_gather_x<<<(NN * FI + 255) / 256, 256, 0, stream>>>(x_idx, node_emb, x_a);
  k_count<<<(NE + 255) / 256, 256, 0, stream>>>(dstp, deg);
  k_scan<<<1, 1024, 0, stream>>>(deg, off, cur);
  k_fill<<<(NE + 255) / 256, 256, 0, stream>>>(srcp, dstp, eattr, cur, csr);
  k_logsum<<<1, 1024, 0, stream>>>(deg, avglog);
  k_scalers<<<(NN + 255) / 256, 256, 0, stream>>>(deg, avglog, ampv, attv, invv);
  k_table_e<<<200, 128, 0, stream>>>(edge_emb, W_edge, b_edge, te);
  k_tbl_m<<<200, 384, 0, stream>>>(te, W_pre, b_pre, tm_bf);
  k_repack_WAs<<<(2 * FI * CH + 255) / 256, 256, 0, stream>>>(W_pre, WAs);
  k_make_V<<<2 * NT * 3, 128, 0, stream>>>(W_pre, W_post, V);
  k_pack_B<<<(230400 + 255) / 256, 256, 0, stream>>>(W_post, V, Bpk);
  k_bias_comb<<<2, 128, 0, stream>>>(b_post, W_lin, b_lin, bc);

  for (int l = 0; l < 2; ++l) {
    const float* xin = (l == 0) ? x_a : x_b;
    float* xout = (l == 0) ? x_b : x_a;
    k_gemm_xs<<<dim3(313, 3), 256, 0, stream>>>(xin, WAs + (size_t)l * FI * CH, xs_bf);
    for (int n0 = 0; n0 < NN; n0 += chunkN) {
      int cn = (NN - n0 < chunkN) ? (NN - n0) : chunkN;
      k_make_xh<<<(cn * 160 + 255) / 256, 256, 0, stream>>>(n0, cn, xin, deg, xh);
      k_aggregate<<<(cn + 1) / 2, 192, 0, stream>>>(n0, cn, xs_bf, csr, off, invv,
                                                    tm_bf + (size_t)l * 100 * 384, aggA);
      k_mfma_post<<<dim3((cn + 31) / 32, 5), 128, 0, stream>>>(
          n0, n0 + cn, aggA, xh, Bpk + (size_t)l * 115200, ampv, attv, z);
    }
    hipMemsetAsync(bnsum, 0, 2 * FI * 4, stream);
    k_gemm75<<<313, 256, 0, stream>>>(z, W_lin + (size_t)l * FI * FI, bc + l * 76,
                                      z, bnsum);
    k_bnfin<<<1, 128, 0, stream>>>(bnsum, gam + l * FI, bet + l * FI, bnsc);
    k_bnapply<<<(NN * FI + 255) / 256, 256, 0, stream>>>(z, bnsc, xout);
  }

  k_pool<<<(NN * FI + 255) / 256, 256, 0, stream>>>(x_a, batch, pooled);
  k_head<<<NG, 64, 0, stream>>>(pooled, W1, b1, W2, b2, W3, b3, (float*)d_out);
}